// Round 1
// baseline (1786.261 us; speedup 1.0000x reference)
//
#include <hip/hip_runtime.h>

typedef _Float16 half8 __attribute__((ext_vector_type(8)));
typedef float float4v __attribute__((ext_vector_type(4)));

// ---------------------------------------------------------------- small ops

__global__ void pool2_kernel(const float* __restrict__ in, float* __restrict__ out) {
    // [64][96][96] -> [64][48][48], 2x2 mean
    int i = blockIdx.x * 256 + threadIdx.x;
    if (i >= 64 * 48 * 48) return;
    int c = i / 2304, r = i % 2304, ph = r / 48, pw = r % 48;
    const float* p = in + c * 9216 + ph * 2 * 96 + pw * 2;
    out[i] = 0.25f * (p[0] + p[1] + p[96] + p[97]);
}

template <int CIN>
__global__ void conv1x1_prelu(const float* __restrict__ in, const float* __restrict__ W,
                              const float* __restrict__ bias, const float* __restrict__ a,
                              float* __restrict__ out, int Cout, int npix) {
    int p = blockIdx.x * blockDim.x + threadIdx.x;
    if (p >= npix) return;
    float xin[CIN];
#pragma unroll
    for (int ci = 0; ci < CIN; ++ci) xin[ci] = in[ci * npix + p];
    float alpha = a[0];
    for (int co = 0; co < Cout; ++co) {
        float s = bias[co];
#pragma unroll
        for (int ci = 0; ci < CIN; ++ci) s += W[co * CIN + ci] * xin[ci];
        out[co * npix + p] = s >= 0.f ? s : alpha * s;
    }
}

// xp[q][c*9+kh*3+kw] = match[c][qh+kh-1][qw+kw-1]  (zero pad), fp16
__global__ void build_xp(const float* __restrict__ match, _Float16* __restrict__ xp) {
    int idx = blockIdx.x * 256 + threadIdx.x;  // q*32 + c
    if (idx >= 9216 * 32) return;
    int q = idx >> 5, c = idx & 31;
    int qh = q / 96, qw = q % 96;
    _Float16* dst = xp + (size_t)q * 288 + c * 9;
#pragma unroll
    for (int kh = 0; kh < 3; ++kh)
#pragma unroll
        for (int kw = 0; kw < 3; ++kw) {
            int y = qh + kh - 1, x = qw + kw - 1;
            float v = (y >= 0 && y < 96 && x >= 0 && x < 96) ? match[c * 9216 + y * 96 + x] : 0.f;
            dst[kh * 3 + kw] = (_Float16)v;
        }
}

// wn[l][c*9+kh*3+kw] = 10 * patch / max(||patch||, 1e-4), fp16.  1 wave per l.
__global__ void build_wn(const float* __restrict__ ref, _Float16* __restrict__ wn) {
    int l = blockIdx.x;  // 2304
    int oh = l / 48, ow = l % 48;
    int lane = threadIdx.x;  // 64
    float vals[5];
    float ss = 0.f;
#pragma unroll
    for (int t = 0; t < 5; ++t) {
        int i = lane + t * 64;
        float v = 0.f;
        if (i < 288) {
            int c = i / 9, r = i % 9, kh = r / 3, kw = r % 3;
            int y = oh + kh - 1, x = ow + kw - 1;
            v = (y >= 0 && y < 48 && x >= 0 && x < 48) ? ref[c * 2304 + y * 48 + x] : 0.f;
        }
        vals[t] = v;
        ss += v * v;
    }
#pragma unroll
    for (int d = 32; d; d >>= 1) ss += __shfl_xor(ss, d);
    float norm = sqrtf(ss);
    norm = norm < 1e-4f ? 1e-4f : norm;
    float inv = 10.f / norm;  // fold SOFTMAX_SCALE here
#pragma unroll
    for (int t = 0; t < 5; ++t) {
        int i = lane + t * 64;
        if (i < 288) wn[(size_t)l * 288 + i] = (_Float16)(vals[t] * inv);
    }
}

// Wt[row=(o*36+i*6+j)][l=(lh*48+lw)] = embed[o][2lh+i-2][2lw+j-2] (zero pad), fp16
__global__ void build_Wt(const float* __restrict__ embed, _Float16* __restrict__ Wt) {
    int idx = blockIdx.x * 256 + threadIdx.x;
    if (idx >= 2304 * 2304) return;
    int row = idx / 2304, l = idx % 2304;
    int o = row / 36, rem = row % 36, i = rem / 6, j = rem % 6;
    int lh = l / 48, lw = l % 48;
    int y = 2 * lh + i - 2, x = 2 * lw + j - 2;
    float v = (y >= 0 && y < 96 && x >= 0 && x < 96) ? embed[o * 9216 + y * 96 + x] : 0.f;
    Wt[idx] = (_Float16)v;
}

// row softmax over l=2304 per q, writes fp16 normalized weights
__global__ __launch_bounds__(256) void softmax_rows(const float* __restrict__ S,
                                                    _Float16* __restrict__ yi) {
    int q = blockIdx.x;
    const float* row = S + (size_t)q * 2304;
    int tid = threadIdx.x;
    float v[9];
    float m = -1e30f;
#pragma unroll
    for (int t = 0; t < 9; ++t) {
        v[t] = row[tid + t * 256];
        m = fmaxf(m, v[t]);
    }
    __shared__ float red[8];
#pragma unroll
    for (int d = 32; d; d >>= 1) m = fmaxf(m, __shfl_xor(m, d));
    if ((tid & 63) == 0) red[tid >> 6] = m;
    __syncthreads();
    m = fmaxf(fmaxf(red[0], red[1]), fmaxf(red[2], red[3]));
    float s = 0.f;
#pragma unroll
    for (int t = 0; t < 9; ++t) {
        v[t] = expf(v[t] - m);
        s += v[t];
    }
#pragma unroll
    for (int d = 32; d; d >>= 1) s += __shfl_xor(s, d);
    __syncthreads();
    if ((tid & 63) == 0) red[(tid >> 6) + 4] = s;
    __syncthreads();
    s = red[4] + red[5] + red[6] + red[7];
    float inv = 1.f / s;
    _Float16* orow = yi + (size_t)q * 2304;
#pragma unroll
    for (int t = 0; t < 9; ++t) orow[tid + t * 256] = (_Float16)(v[t] * inv);
}

// ---------------------------------------------------------------- MFMA GEMM
// C[M][N] = sum_k A[M][K] * B[N][K]   (both K-contiguous fp16), fp32 accum.
// MODE 0: store C to out (GEMM1, logits — scale already folded into B)
// MODE 1: scatter-add C[(o,i,j),(h,w)] into yt[o][2h+i-2][2w+j-2] (tconv)
template <int MODE>
__global__ __launch_bounds__(256) void gemm16(const _Float16* __restrict__ A,
                                              const _Float16* __restrict__ B, int M, int N, int K,
                                              float* __restrict__ out, float* __restrict__ yt) {
    __shared__ _Float16 As[128][40];  // stride 40 halves = 80 B (16B-aligned, conflict-light)
    __shared__ _Float16 Bs[128][40];
    int tid = threadIdx.x;
    int wave = tid >> 6, lane = tid & 63;
    int wm = wave >> 1, wn_ = wave & 1;  // 2x2 wave grid, 64x64 per wave
    int quad = lane >> 4, mrow = lane & 15;
    int m0 = blockIdx.y * 128, n0 = blockIdx.x * 128;
    float4v acc[4][4] = {};

    for (int k0 = 0; k0 < K; k0 += 32) {
        // stage 128x32 halves of A and B: 512 16B-chunks each, 2+2 per thread
#pragma unroll
        for (int r = 0; r < 2; ++r) {
            int c = tid + r * 256;  // 0..511
            int row = c >> 2, cc = c & 3;
            *(uint4*)(&As[row][cc * 8]) =
                *(const uint4*)(A + (size_t)(m0 + row) * K + k0 + cc * 8);
            *(uint4*)(&Bs[row][cc * 8]) =
                *(const uint4*)(B + (size_t)(n0 + row) * K + k0 + cc * 8);
        }
        __syncthreads();
        half8 af[4], bf[4];
#pragma unroll
        for (int t = 0; t < 4; ++t) {
            af[t] = *(const half8*)(&As[wm * 64 + t * 16 + mrow][quad * 8]);
            bf[t] = *(const half8*)(&Bs[wn_ * 64 + t * 16 + mrow][quad * 8]);
        }
#pragma unroll
        for (int i = 0; i < 4; ++i)
#pragma unroll
            for (int j = 0; j < 4; ++j)
                acc[i][j] = __builtin_amdgcn_mfma_f32_16x16x32_f16(af[i], bf[j], acc[i][j], 0, 0, 0);
        __syncthreads();
    }

    // epilogue: D row m = quad*4+r (M dim), col n = lane&15 (N dim)
#pragma unroll
    for (int i = 0; i < 4; ++i)
#pragma unroll
        for (int j = 0; j < 4; ++j)
#pragma unroll
            for (int r = 0; r < 4; ++r) {
                int row = m0 + wm * 64 + i * 16 + quad * 4 + r;
                int col = n0 + wn_ * 64 + j * 16 + mrow;
                float v = acc[i][j][r];
                if (MODE == 0) {
                    out[(size_t)row * N + col] = v;
                } else {
                    int o = row / 36, rem = row % 36, ii = rem / 6, jj = rem % 6;
                    int h = col / 96, w = col % 96;
                    int Y = 2 * h + ii - 2, X = 2 * w + jj - 2;
                    if (Y >= 0 && Y < 192 && X >= 0 && X < 192)
                        atomicAdd(yt + o * 36864 + Y * 192 + X, v);
                }
            }
}

// down: 3x3 conv stride 2 pad 1 on yt[64][192][192], + bd, /6 -> out[64][96][96]
__global__ __launch_bounds__(256) void down_conv(const float* __restrict__ yt,
                                                 const float* __restrict__ Wd,
                                                 const float* __restrict__ bd,
                                                 float* __restrict__ out) {
    int blk = blockIdx.x;  // 48*48 blocks of 2x2 output pixels
    int by = (blk / 48) * 2, bx = (blk % 48) * 2;
    int tid = threadIdx.x;
    int op = tid & 63, p = tid >> 6;  // o' x 4 pixels
    int y = by + (p >> 1), x = bx + (p & 1);
    __shared__ float tile[64][5][5];
    for (int i = tid; i < 1600; i += 256) {
        int o = i / 25, r = i % 25, dy = r / 5, dx = r % 5;
        int Y = 2 * by - 1 + dy, X = 2 * bx - 1 + dx;
        tile[o][dy][dx] = (Y >= 0 && Y < 192 && X >= 0 && X < 192) ? yt[o * 36864 + Y * 192 + X] : 0.f;
    }
    __syncthreads();
    float s = bd[op];
    int oy = (p >> 1) * 2, ox = (p & 1) * 2;
    for (int o = 0; o < 64; ++o)
#pragma unroll
        for (int dy = 0; dy < 3; ++dy)
#pragma unroll
            for (int dx = 0; dx < 3; ++dx)
                s += Wd[(op * 64 + o) * 9 + dy * 3 + dx] * tile[o][oy + dy][ox + dx];
    out[op * 9216 + y * 96 + x] = s * (1.f / 6.f);
}

// ---------------------------------------------------------------- launch

extern "C" void kernel_launch(void* const* d_in, const int* in_sizes, int n_in,
                              void* d_out, int out_size, void* d_ws, size_t ws_size,
                              hipStream_t stream) {
    const float* x = (const float*)d_in[0];
    const float* W1 = (const float*)d_in[1];
    const float* b1 = (const float*)d_in[2];
    const float* a1 = (const float*)d_in[3];
    const float* W2 = (const float*)d_in[4];
    const float* b2 = (const float*)d_in[5];
    const float* a2 = (const float*)d_in[6];
    const float* Wa = (const float*)d_in[7];
    const float* ba = (const float*)d_in[8];
    const float* aa = (const float*)d_in[9];
    const float* Wd = (const float*)d_in[10];
    const float* bd = (const float*)d_in[11];
    float* out = (float*)d_out;

    char* ws = (char*)d_ws;
    float* S = (float*)ws;          ws += 84934656;   // [9216][2304] fp32 logits
    _Float16* yi = (_Float16*)ws;   ws += 42467328;   // [9216][2304] fp16 softmax
    _Float16* Wt = (_Float16*)ws;   ws += 10616832;   // [2304][2304] fp16 raw_w^T
    _Float16* xp = (_Float16*)ws;   ws += 5308416;    // [9216][288] fp16
    _Float16* wn = (_Float16*)ws;   ws += 1327104;    // [2304][288] fp16 (x10 folded)
    float* embed = (float*)ws;      ws += 2359296;    // [64][96][96]
    float* match = (float*)ws;      ws += 1179648;    // [32][96][96]
    float* pooled = (float*)ws;     ws += 589824;     // [64][48][48]
    float* refb = (float*)ws;       ws += 294912;     // [32][48][48]
    float* yt = (float*)ws;         ws += 9437184;    // [64][192][192]

    for (int b = 0; b < 2; ++b) {
        const float* xb = x + (size_t)b * 64 * 9216;
        float* outb = out + (size_t)b * 64 * 9216;

        pool2_kernel<<<576, 256, 0, stream>>>(xb, pooled);
        conv1x1_prelu<64><<<36, 256, 0, stream>>>(xb, Wa, ba, aa, embed, 64, 9216);
        conv1x1_prelu<64><<<36, 256, 0, stream>>>(xb, W1, b1, a1, match, 32, 9216);
        conv1x1_prelu<64><<<9, 256, 0, stream>>>(pooled, W2, b2, a2, refb, 32, 2304);
        build_xp<<<1152, 256, 0, stream>>>(match, xp);
        build_wn<<<2304, 64, 0, stream>>>(refb, wn);
        build_Wt<<<20736, 256, 0, stream>>>(embed, Wt);

        // GEMM1: S[q][l] = <xp[q], wn[l]> (x10 folded into wn)
        gemm16<0><<<dim3(18, 72), 256, 0, stream>>>(xp, wn, 9216, 2304, 288, S, nullptr);
        softmax_rows<<<9216, 256, 0, stream>>>(S, yi);

        hipMemsetAsync(yt, 0, 9437184, stream);
        // GEMM2: Z[(oij)][q] = sum_l Wt[(oij)][l] * yi[q][l], scatter into yt
        gemm16<1><<<dim3(72, 18), 256, 0, stream>>>(Wt, yi, 2304, 9216, 2304, nullptr, yt);

        down_conv<<<2304, 256, 0, stream>>>(yt, Wd, bd, outb);
    }
}

// Round 3
// 1277.151 us; speedup vs baseline: 1.3986x; 1.3986x over previous
//
#include <hip/hip_runtime.h>

typedef _Float16 half8 __attribute__((ext_vector_type(8)));
typedef float float4v __attribute__((ext_vector_type(4)));

// ---------------------------------------------------------------- small ops

__global__ void pool2_kernel(const float* __restrict__ in, float* __restrict__ out) {
    // [64][96][96] -> [64][48][48], 2x2 mean
    int i = blockIdx.x * 256 + threadIdx.x;
    if (i >= 64 * 48 * 48) return;
    int c = i / 2304, r = i % 2304, ph = r / 48, pw = r % 48;
    const float* p = in + c * 9216 + ph * 2 * 96 + pw * 2;
    out[i] = 0.25f * (p[0] + p[1] + p[96] + p[97]);
}

template <int CIN>
__global__ void conv1x1_prelu(const float* __restrict__ in, const float* __restrict__ W,
                              const float* __restrict__ bias, const float* __restrict__ a,
                              float* __restrict__ out, int Cout, int npix) {
    int p = blockIdx.x * blockDim.x + threadIdx.x;
    if (p >= npix) return;
    float xin[CIN];
#pragma unroll
    for (int ci = 0; ci < CIN; ++ci) xin[ci] = in[ci * npix + p];
    float alpha = a[0];
    for (int co = 0; co < Cout; ++co) {
        float s = bias[co];
#pragma unroll
        for (int ci = 0; ci < CIN; ++ci) s += W[co * CIN + ci] * xin[ci];
        out[co * npix + p] = s >= 0.f ? s : alpha * s;
    }
}

// xp[q][c*9+kh*3+kw] = match[c][qh+kh-1][qw+kw-1]  (zero pad), fp16
__global__ void build_xp(const float* __restrict__ match, _Float16* __restrict__ xp) {
    int idx = blockIdx.x * 256 + threadIdx.x;  // q*32 + c
    if (idx >= 9216 * 32) return;
    int q = idx >> 5, c = idx & 31;
    int qh = q / 96, qw = q % 96;
    _Float16* dst = xp + (size_t)q * 288 + c * 9;
#pragma unroll
    for (int kh = 0; kh < 3; ++kh)
#pragma unroll
        for (int kw = 0; kw < 3; ++kw) {
            int y = qh + kh - 1, x = qw + kw - 1;
            float v = (y >= 0 && y < 96 && x >= 0 && x < 96) ? match[c * 9216 + y * 96 + x] : 0.f;
            dst[kh * 3 + kw] = (_Float16)v;
        }
}

// wn[l][c*9+kh*3+kw] = 10 * patch / max(||patch||, 1e-4), fp16.  1 wave per l.
__global__ void build_wn(const float* __restrict__ ref, _Float16* __restrict__ wn) {
    int l = blockIdx.x;  // 2304
    int oh = l / 48, ow = l % 48;
    int lane = threadIdx.x;  // 64
    float vals[5];
    float ss = 0.f;
#pragma unroll
    for (int t = 0; t < 5; ++t) {
        int i = lane + t * 64;
        float v = 0.f;
        if (i < 288) {
            int c = i / 9, r = i % 9, kh = r / 3, kw = r % 3;
            int y = oh + kh - 1, x = ow + kw - 1;
            v = (y >= 0 && y < 48 && x >= 0 && x < 48) ? ref[c * 2304 + y * 48 + x] : 0.f;
        }
        vals[t] = v;
        ss += v * v;
    }
#pragma unroll
    for (int d = 32; d; d >>= 1) ss += __shfl_xor(ss, d);
    float norm = sqrtf(ss);
    norm = norm < 1e-4f ? 1e-4f : norm;
    float inv = 10.f / norm;  // fold SOFTMAX_SCALE here
#pragma unroll
    for (int t = 0; t < 5; ++t) {
        int i = lane + t * 64;
        if (i < 288) wn[(size_t)l * 288 + i] = (_Float16)(vals[t] * inv);
    }
}

// Wt[row=(o*36+i*6+j)][l=(lh*48+lw)] = embed[o][2lh+i-2][2lw+j-2] (zero pad), fp16
__global__ void build_Wt(const float* __restrict__ embed, _Float16* __restrict__ Wt) {
    int idx = blockIdx.x * 256 + threadIdx.x;
    if (idx >= 2304 * 2304) return;
    int row = idx / 2304, l = idx % 2304;
    int o = row / 36, rem = row % 36, i = rem / 6, j = rem % 6;
    int lh = l / 48, lw = l % 48;
    int y = 2 * lh + i - 2, x = 2 * lw + j - 2;
    float v = (y >= 0 && y < 96 && x >= 0 && x < 96) ? embed[o * 9216 + y * 96 + x] : 0.f;
    Wt[idx] = (_Float16)v;
}

// row softmax over l=2304 per q, writes fp16 normalized weights
__global__ __launch_bounds__(256) void softmax_rows(const float* __restrict__ S,
                                                    _Float16* __restrict__ yi) {
    int q = blockIdx.x;
    const float* row = S + (size_t)q * 2304;
    int tid = threadIdx.x;
    float v[9];
    float m = -1e30f;
#pragma unroll
    for (int t = 0; t < 9; ++t) {
        v[t] = row[tid + t * 256];
        m = fmaxf(m, v[t]);
    }
    __shared__ float red[8];
#pragma unroll
    for (int d = 32; d; d >>= 1) m = fmaxf(m, __shfl_xor(m, d));
    if ((tid & 63) == 0) red[tid >> 6] = m;
    __syncthreads();
    m = fmaxf(fmaxf(red[0], red[1]), fmaxf(red[2], red[3]));
    float s = 0.f;
#pragma unroll
    for (int t = 0; t < 9; ++t) {
        v[t] = expf(v[t] - m);
        s += v[t];
    }
#pragma unroll
    for (int d = 32; d; d >>= 1) s += __shfl_xor(s, d);
    __syncthreads();
    if ((tid & 63) == 0) red[(tid >> 6) + 4] = s;
    __syncthreads();
    s = red[4] + red[5] + red[6] + red[7];
    float inv = 1.f / s;
    _Float16* orow = yi + (size_t)q * 2304;
#pragma unroll
    for (int t = 0; t < 9; ++t) orow[tid + t * 256] = (_Float16)(v[t] * inv);
}

// ---------------------------------------------------------------- MFMA GEMM
// C[M][N] = sum_k A[M][K] * B[N][K]  (K-contiguous fp16), fp32 out, plain store.
// Staging: global_load_lds width-16. Tile = 128 rows x 32 halves = 8 x 1KB chunks
// per matrix; each wave issues 2 A-chunks + 2 B-chunks (c = wave*2 + r, r<2).
// XOR swizzle slot = cc ^ ((row>>1)&3) keeps ds_read_b128 at 2-way/bank (free).
__global__ __launch_bounds__(256) void gemm16(const _Float16* __restrict__ A,
                                              const _Float16* __restrict__ B, int M, int N, int K,
                                              float* __restrict__ out) {
    __shared__ _Float16 As[128 * 32];
    __shared__ _Float16 Bs[128 * 32];
    int tid = threadIdx.x;
    int wave = tid >> 6, lane = tid & 63;
    int wm = wave >> 1, wn_ = wave & 1;  // 2x2 wave grid, 64x64 per wave
    int quad = lane >> 4, mrow = lane & 15;
    int m0 = blockIdx.y * 128, n0 = blockIdx.x * 128;
    int lrow = lane >> 2, lslot = lane & 3;
    float4v acc[4][4] = {};

    for (int k0 = 0; k0 < K; k0 += 32) {
        // chunk c = rows [c*16, c*16+16); lane writes LDS at chunk_base + lane*16B
        // (hardware layout), so source element = (row = c*16 + lane/4,
        //  cc = (lane&3) ^ ((row>>1)&3)) — the inverse of the read swizzle.
#pragma unroll
        for (int r = 0; r < 2; ++r) {
            int c = wave * 2 + r;  // 0..7 — exactly 8 chunks per matrix
            int row = c * 16 + lrow;
            int cc = lslot ^ ((row >> 1) & 3);
            const _Float16* ga = A + (size_t)(m0 + row) * K + k0 + cc * 8;
            const _Float16* gb = B + (size_t)(n0 + row) * K + k0 + cc * 8;
            __builtin_amdgcn_global_load_lds(
                (const __attribute__((address_space(1))) unsigned int*)ga,
                (__attribute__((address_space(3))) unsigned int*)&As[c * 512], 16, 0, 0);
            __builtin_amdgcn_global_load_lds(
                (const __attribute__((address_space(1))) unsigned int*)gb,
                (__attribute__((address_space(3))) unsigned int*)&Bs[c * 512], 16, 0, 0);
        }
        __syncthreads();
        half8 af[4], bf[4];
#pragma unroll
        for (int t = 0; t < 4; ++t) {
            int arow = wm * 64 + t * 16 + mrow;
            af[t] = *(const half8*)&As[arow * 32 + (quad ^ ((arow >> 1) & 3)) * 8];
            int brow = wn_ * 64 + t * 16 + mrow;
            bf[t] = *(const half8*)&Bs[brow * 32 + (quad ^ ((brow >> 1) & 3)) * 8];
        }
#pragma unroll
        for (int i = 0; i < 4; ++i)
#pragma unroll
            for (int j = 0; j < 4; ++j)
                acc[i][j] = __builtin_amdgcn_mfma_f32_16x16x32_f16(af[i], bf[j], acc[i][j], 0, 0, 0);
        __syncthreads();
    }

    // epilogue: D row m = quad*4+r (M dim), col n = lane&15 (N dim) — plain stores
#pragma unroll
    for (int i = 0; i < 4; ++i)
#pragma unroll
        for (int j = 0; j < 4; ++j)
#pragma unroll
            for (int r = 0; r < 4; ++r) {
                int row = m0 + wm * 64 + i * 16 + quad * 4 + r;
                int col = n0 + wn_ * 64 + j * 16 + mrow;
                out[(size_t)row * N + col] = acc[i][j][r];
            }
}

// gather (inverse of tconv scatter): yt[o][Y][X] = sum_{i==Y%2, j==X%2 (mod 2)}
//   Z[(o*36+i*6+j)][h*96+w]  with h=(Y+2-i)/2, w=(X+2-j)/2 in range. No atomics.
__global__ void gather_yt(const float* __restrict__ Z, float* __restrict__ yt) {
    int idx = blockIdx.x * 256 + threadIdx.x;
    if (idx >= 64 * 192 * 192) return;
    int o = idx / 36864, r = idx % 36864, Y = r / 192, X = r % 192;
    float s = 0.f;
    for (int i = Y & 1; i < 6; i += 2) {
        int h2 = Y + 2 - i;
        if (h2 < 0) continue;
        int h = h2 >> 1;
        if (h >= 96) continue;
        for (int j = X & 1; j < 6; j += 2) {
            int w2 = X + 2 - j;
            if (w2 < 0) continue;
            int w = w2 >> 1;
            if (w >= 96) continue;
            s += Z[(size_t)(o * 36 + i * 6 + j) * 9216 + h * 96 + w];
        }
    }
    yt[idx] = s;
}

// down: 3x3 conv stride 2 pad 1 on yt[64][192][192], + bd, /6 -> out[64][96][96]
__global__ __launch_bounds__(256) void down_conv(const float* __restrict__ yt,
                                                 const float* __restrict__ Wd,
                                                 const float* __restrict__ bd,
                                                 float* __restrict__ out) {
    int blk = blockIdx.x;  // 48*48 blocks of 2x2 output pixels
    int by = (blk / 48) * 2, bx = (blk % 48) * 2;
    int tid = threadIdx.x;
    int op = tid & 63, p = tid >> 6;  // o' x 4 pixels
    int y = by + (p >> 1), x = bx + (p & 1);
    __shared__ float tile[64][5][5];
    for (int i = tid; i < 1600; i += 256) {
        int o = i / 25, r = i % 25, dy = r / 5, dx = r % 5;
        int Y = 2 * by - 1 + dy, X = 2 * bx - 1 + dx;
        tile[o][dy][dx] = (Y >= 0 && Y < 192 && X >= 0 && X < 192) ? yt[o * 36864 + Y * 192 + X] : 0.f;
    }
    __syncthreads();
    float s = bd[op];
    int oy = (p >> 1) * 2, ox = (p & 1) * 2;
    for (int o = 0; o < 64; ++o)
#pragma unroll
        for (int dy = 0; dy < 3; ++dy)
#pragma unroll
            for (int dx = 0; dx < 3; ++dx)
                s += Wd[(op * 64 + o) * 9 + dy * 3 + dx] * tile[o][oy + dy][ox + dx];
    out[op * 9216 + y * 96 + x] = s * (1.f / 6.f);
}

// ---------------------------------------------------------------- launch

extern "C" void kernel_launch(void* const* d_in, const int* in_sizes, int n_in,
                              void* d_out, int out_size, void* d_ws, size_t ws_size,
                              hipStream_t stream) {
    const float* x = (const float*)d_in[0];
    const float* W1 = (const float*)d_in[1];
    const float* b1 = (const float*)d_in[2];
    const float* a1 = (const float*)d_in[3];
    const float* W2 = (const float*)d_in[4];
    const float* b2 = (const float*)d_in[5];
    const float* a2 = (const float*)d_in[6];
    const float* Wa = (const float*)d_in[7];
    const float* ba = (const float*)d_in[8];
    const float* aa = (const float*)d_in[9];
    const float* Wd = (const float*)d_in[10];
    const float* bd = (const float*)d_in[11];
    float* out = (float*)d_out;

    char* ws = (char*)d_ws;
    float* S = (float*)ws;          ws += 84934656;   // [9216][2304] logits; reused as Z [2304][9216]
    _Float16* yi = (_Float16*)ws;   ws += 42467328;   // [9216][2304] fp16 softmax
    _Float16* Wt = (_Float16*)ws;   ws += 10616832;   // [2304][2304] fp16 raw_w^T
    _Float16* xp = (_Float16*)ws;   ws += 5308416;    // [9216][288] fp16
    _Float16* wn = (_Float16*)ws;   ws += 1327104;    // [2304][288] fp16 (x10 folded)
    float* embed = (float*)ws;      ws += 2359296;    // [64][96][96]
    float* match = (float*)ws;      ws += 1179648;    // [32][96][96]
    float* pooled = (float*)ws;     ws += 589824;     // [64][48][48]
    float* refb = (float*)ws;       ws += 294912;     // [32][48][48]
    float* yt = (float*)ws;         ws += 9437184;    // [64][192][192]

    for (int b = 0; b < 2; ++b) {
        const float* xb = x + (size_t)b * 64 * 9216;
        float* outb = out + (size_t)b * 64 * 9216;

        pool2_kernel<<<576, 256, 0, stream>>>(xb, pooled);
        conv1x1_prelu<64><<<36, 256, 0, stream>>>(xb, Wa, ba, aa, embed, 64, 9216);
        conv1x1_prelu<64><<<36, 256, 0, stream>>>(xb, W1, b1, a1, match, 32, 9216);
        conv1x1_prelu<64><<<9, 256, 0, stream>>>(pooled, W2, b2, a2, refb, 32, 2304);
        build_xp<<<1152, 256, 0, stream>>>(match, xp);
        build_wn<<<2304, 64, 0, stream>>>(refb, wn);
        build_Wt<<<20736, 256, 0, stream>>>(embed, Wt);

        // GEMM1: S[q][l] = <xp[q], wn[l]> (x10 folded into wn)
        gemm16<<<dim3(18, 72), 256, 0, stream>>>(xp, wn, 9216, 2304, 288, S);
        softmax_rows<<<9216, 256, 0, stream>>>(S, yi);

        // GEMM2: Z[(oij)][q] = sum_l Wt[(oij)][l] * yi[q][l]  (plain store into S)
        gemm16<<<dim3(72, 18), 256, 0, stream>>>(Wt, yi, 2304, 9216, 2304, S);

        gather_yt<<<9216, 256, 0, stream>>>(S, yt);
        down_conv<<<2304, 256, 0, stream>>>(yt, Wd, bd, outb);
    }
}

// Round 4
// 998.550 us; speedup vs baseline: 1.7889x; 1.2790x over previous
//
#include <hip/hip_runtime.h>

typedef _Float16 half8 __attribute__((ext_vector_type(8)));
typedef float float4v __attribute__((ext_vector_type(4)));

// ---------------------------------------------------------------- small ops

__global__ void pool2_kernel(const float* __restrict__ in, float* __restrict__ out) {
    // [64][96][96] -> [64][48][48], 2x2 mean
    int i = blockIdx.x * 256 + threadIdx.x;
    if (i >= 64 * 48 * 48) return;
    int c = i / 2304, r = i % 2304, ph = r / 48, pw = r % 48;
    const float* p = in + c * 9216 + ph * 2 * 96 + pw * 2;
    out[i] = 0.25f * (p[0] + p[1] + p[96] + p[97]);
}

template <int CIN>
__global__ void conv1x1_prelu(const float* __restrict__ in, const float* __restrict__ W,
                              const float* __restrict__ bias, const float* __restrict__ a,
                              float* __restrict__ out, int Cout, int npix) {
    int p = blockIdx.x * blockDim.x + threadIdx.x;
    if (p >= npix) return;
    float xin[CIN];
#pragma unroll
    for (int ci = 0; ci < CIN; ++ci) xin[ci] = in[ci * npix + p];
    float alpha = a[0];
    for (int co = 0; co < Cout; ++co) {
        float s = bias[co];
#pragma unroll
        for (int ci = 0; ci < CIN; ++ci) s += W[co * CIN + ci] * xin[ci];
        out[co * npix + p] = s >= 0.f ? s : alpha * s;
    }
}

// xp[q][c*9+kh*3+kw] = match[c][qh+kh-1][qw+kw-1]  (zero pad), fp16
__global__ void build_xp(const float* __restrict__ match, _Float16* __restrict__ xp) {
    int idx = blockIdx.x * 256 + threadIdx.x;  // q*32 + c
    if (idx >= 9216 * 32) return;
    int q = idx >> 5, c = idx & 31;
    int qh = q / 96, qw = q % 96;
    _Float16* dst = xp + (size_t)q * 288 + c * 9;
#pragma unroll
    for (int kh = 0; kh < 3; ++kh)
#pragma unroll
        for (int kw = 0; kw < 3; ++kw) {
            int y = qh + kh - 1, x = qw + kw - 1;
            float v = (y >= 0 && y < 96 && x >= 0 && x < 96) ? match[c * 9216 + y * 96 + x] : 0.f;
            dst[kh * 3 + kw] = (_Float16)v;
        }
}

// wn[l][c*9+kh*3+kw] = 10 * patch / max(||patch||, 1e-4), fp16.  1 wave per l.
__global__ void build_wn(const float* __restrict__ ref, _Float16* __restrict__ wn) {
    int l = blockIdx.x;  // 2304
    int oh = l / 48, ow = l % 48;
    int lane = threadIdx.x;  // 64
    float vals[5];
    float ss = 0.f;
#pragma unroll
    for (int t = 0; t < 5; ++t) {
        int i = lane + t * 64;
        float v = 0.f;
        if (i < 288) {
            int c = i / 9, r = i % 9, kh = r / 3, kw = r % 3;
            int y = oh + kh - 1, x = ow + kw - 1;
            v = (y >= 0 && y < 48 && x >= 0 && x < 48) ? ref[c * 2304 + y * 48 + x] : 0.f;
        }
        vals[t] = v;
        ss += v * v;
    }
#pragma unroll
    for (int d = 32; d; d >>= 1) ss += __shfl_xor(ss, d);
    float norm = sqrtf(ss);
    norm = norm < 1e-4f ? 1e-4f : norm;
    float inv = 10.f / norm;  // fold SOFTMAX_SCALE here
#pragma unroll
    for (int t = 0; t < 5; ++t) {
        int i = lane + t * 64;
        if (i < 288) wn[(size_t)l * 288 + i] = (_Float16)(vals[t] * inv);
    }
}

// Wt[row=(o*36+i*6+j)][l=(lh*48+lw)] = embed[o][2lh+i-2][2lw+j-2] (zero pad), fp16
__global__ void build_Wt(const float* __restrict__ embed, _Float16* __restrict__ Wt) {
    int idx = blockIdx.x * 256 + threadIdx.x;
    if (idx >= 2304 * 2304) return;
    int row = idx / 2304, l = idx % 2304;
    int o = row / 36, rem = row % 36, i = rem / 6, j = rem % 6;
    int lh = l / 48, lw = l % 48;
    int y = 2 * lh + i - 2, x = 2 * lw + j - 2;
    float v = (y >= 0 && y < 96 && x >= 0 && x < 96) ? embed[o * 9216 + y * 96 + x] : 0.f;
    Wt[idx] = (_Float16)v;
}

// row softmax over l=2304 per q, writes fp16 normalized weights
__global__ __launch_bounds__(256) void softmax_rows(const float* __restrict__ S,
                                                    _Float16* __restrict__ yi) {
    int q = blockIdx.x;
    const float* row = S + (size_t)q * 2304;
    int tid = threadIdx.x;
    float v[9];
    float m = -1e30f;
#pragma unroll
    for (int t = 0; t < 9; ++t) {
        v[t] = row[tid + t * 256];
        m = fmaxf(m, v[t]);
    }
    __shared__ float red[8];
#pragma unroll
    for (int d = 32; d; d >>= 1) m = fmaxf(m, __shfl_xor(m, d));
    if ((tid & 63) == 0) red[tid >> 6] = m;
    __syncthreads();
    m = fmaxf(fmaxf(red[0], red[1]), fmaxf(red[2], red[3]));
    float s = 0.f;
#pragma unroll
    for (int t = 0; t < 9; ++t) {
        v[t] = expf(v[t] - m);
        s += v[t];
    }
#pragma unroll
    for (int d = 32; d; d >>= 1) s += __shfl_xor(s, d);
    __syncthreads();
    if ((tid & 63) == 0) red[(tid >> 6) + 4] = s;
    __syncthreads();
    s = red[4] + red[5] + red[6] + red[7];
    float inv = 1.f / s;
    _Float16* orow = yi + (size_t)q * 2304;
#pragma unroll
    for (int t = 0; t < 9; ++t) orow[tid + t * 256] = (_Float16)(v[t] * inv);
}

// ---------------------------------------------------------------- MFMA GEMM
// C[M][N] = sum_k A[M][K] * B[N][K]  (K-contiguous fp16), fp32 accum.
// MODE 0: plain store.  MODE 2: rows<64 only, val=(acc+bias[row])/6 (down conv).
// Staging: global_load_lds width-16. Tile = 128 rows x 32 halves = 8 x 1KB chunks
// per matrix; each wave issues 2 A-chunks + 2 B-chunks (c = wave*2 + r, r<2).
// XOR swizzle slot = cc ^ ((row>>1)&3) keeps ds_read_b128 at 2-way/bank (free).
template <int MODE>
__global__ __launch_bounds__(256) void gemm16(const _Float16* __restrict__ A,
                                              const _Float16* __restrict__ B, int M, int N, int K,
                                              float* __restrict__ out,
                                              const float* __restrict__ bias) {
    __shared__ _Float16 As[128 * 32];
    __shared__ _Float16 Bs[128 * 32];
    int tid = threadIdx.x;
    int wave = tid >> 6, lane = tid & 63;
    int wm = wave >> 1, wn_ = wave & 1;  // 2x2 wave grid, 64x64 per wave
    int quad = lane >> 4, mrow = lane & 15;
    int m0 = blockIdx.y * 128, n0 = blockIdx.x * 128;
    int lrow = lane >> 2, lslot = lane & 3;
    float4v acc[4][4] = {};

    for (int k0 = 0; k0 < K; k0 += 32) {
        // chunk c = rows [c*16, c*16+16); lane writes LDS at chunk_base + lane*16B
        // (hardware layout), so source element = (row = c*16 + lane/4,
        //  cc = (lane&3) ^ ((row>>1)&3)) — the inverse of the read swizzle.
#pragma unroll
        for (int r = 0; r < 2; ++r) {
            int c = wave * 2 + r;  // 0..7 — exactly 8 chunks per matrix
            int row = c * 16 + lrow;
            int cc = lslot ^ ((row >> 1) & 3);
            const _Float16* ga = A + (size_t)(m0 + row) * K + k0 + cc * 8;
            const _Float16* gb = B + (size_t)(n0 + row) * K + k0 + cc * 8;
            __builtin_amdgcn_global_load_lds(
                (const __attribute__((address_space(1))) unsigned int*)ga,
                (__attribute__((address_space(3))) unsigned int*)&As[c * 512], 16, 0, 0);
            __builtin_amdgcn_global_load_lds(
                (const __attribute__((address_space(1))) unsigned int*)gb,
                (__attribute__((address_space(3))) unsigned int*)&Bs[c * 512], 16, 0, 0);
        }
        __syncthreads();
        half8 af[4], bf[4];
#pragma unroll
        for (int t = 0; t < 4; ++t) {
            int arow = wm * 64 + t * 16 + mrow;
            af[t] = *(const half8*)&As[arow * 32 + (quad ^ ((arow >> 1) & 3)) * 8];
            int brow = wn_ * 64 + t * 16 + mrow;
            bf[t] = *(const half8*)&Bs[brow * 32 + (quad ^ ((brow >> 1) & 3)) * 8];
        }
#pragma unroll
        for (int i = 0; i < 4; ++i)
#pragma unroll
            for (int j = 0; j < 4; ++j)
                acc[i][j] = __builtin_amdgcn_mfma_f32_16x16x32_f16(af[i], bf[j], acc[i][j], 0, 0, 0);
        __syncthreads();
    }

    // epilogue: D row m = quad*4+r (M dim), col n = lane&15 (N dim)
#pragma unroll
    for (int i = 0; i < 4; ++i)
#pragma unroll
        for (int j = 0; j < 4; ++j)
#pragma unroll
            for (int r = 0; r < 4; ++r) {
                int row = m0 + wm * 64 + i * 16 + quad * 4 + r;
                int col = n0 + wn_ * 64 + j * 16 + mrow;
                float v = acc[i][j][r];
                if (MODE == 0) {
                    out[(size_t)row * N + col] = v;
                } else {
                    if (row < 64) out[(size_t)row * N + col] = (v + bias[row]) * (1.f / 6.f);
                }
            }
}

// gather (inverse of tconv scatter): yth[o][Y][X] = sum_{i==Y%2, j==X%2 (mod 2)}
//   Z[(o*36+i*6+j)][h*96+w]  with h=(Y+2-i)/2, w=(X+2-j)/2 in range. fp16 out.
__global__ void gather_yt(const float* __restrict__ Z, _Float16* __restrict__ yth) {
    int idx = blockIdx.x * 256 + threadIdx.x;
    if (idx >= 64 * 192 * 192) return;
    int o = idx / 36864, r = idx % 36864, Y = r / 192, X = r % 192;
    float s = 0.f;
    for (int i = Y & 1; i < 6; i += 2) {
        int h2 = Y + 2 - i;
        if (h2 < 0) continue;
        int h = h2 >> 1;
        if (h >= 96) continue;
        for (int j = X & 1; j < 6; j += 2) {
            int w2 = X + 2 - j;
            if (w2 < 0) continue;
            int w = w2 >> 1;
            if (w >= 96) continue;
            s += Z[(size_t)(o * 36 + i * 6 + j) * 9216 + h * 96 + w];
        }
    }
    yth[idx] = (_Float16)s;
}

// im2col for the down conv (3x3, stride 2, pad 1):
// P[q=(y*96+x)][o*9+dy*3+dx] = yth[o][2y-1+dy][2x-1+dx] (zero pad), fp16
__global__ void build_P(const _Float16* __restrict__ yth, _Float16* __restrict__ P) {
    int idx = blockIdx.x * 256 + threadIdx.x;  // q*64 + o
    if (idx >= 9216 * 64) return;
    int q = idx >> 6, o = idx & 63;
    int y = q / 96, x = q % 96;
    _Float16* dst = P + (size_t)q * 576 + o * 9;
#pragma unroll
    for (int dy = 0; dy < 3; ++dy)
#pragma unroll
        for (int dx = 0; dx < 3; ++dx) {
            int Y = 2 * y - 1 + dy, X = 2 * x - 1 + dx;
            _Float16 v = (_Float16)0.f;
            if (Y >= 0 && Y < 192 && X >= 0 && X < 192) v = yth[o * 36864 + Y * 192 + X];
            dst[dy * 3 + dx] = v;
        }
}

// Wdh[op][k] fp16, rows 64..127 zero-padded (so the 128-row GEMM tile is safe)
__global__ void build_Wdh(const float* __restrict__ Wd, _Float16* __restrict__ Wdh) {
    int idx = blockIdx.x * 256 + threadIdx.x;
    if (idx >= 128 * 576) return;
    int op = idx / 576;
    Wdh[idx] = (_Float16)(op < 64 ? Wd[idx] : 0.f);  // Wd[(op*64+o)*9+k] == Wd[op*576+...]
}

// ---------------------------------------------------------------- launch

extern "C" void kernel_launch(void* const* d_in, const int* in_sizes, int n_in,
                              void* d_out, int out_size, void* d_ws, size_t ws_size,
                              hipStream_t stream) {
    const float* x = (const float*)d_in[0];
    const float* W1 = (const float*)d_in[1];
    const float* b1 = (const float*)d_in[2];
    const float* a1 = (const float*)d_in[3];
    const float* W2 = (const float*)d_in[4];
    const float* b2 = (const float*)d_in[5];
    const float* a2 = (const float*)d_in[6];
    const float* Wa = (const float*)d_in[7];
    const float* ba = (const float*)d_in[8];
    const float* aa = (const float*)d_in[9];
    const float* Wd = (const float*)d_in[10];
    const float* bd = (const float*)d_in[11];
    float* out = (float*)d_out;

    char* ws = (char*)d_ws;
    float* S = (float*)ws;          ws += 84934656;   // [9216][2304] logits; reused as Z [2304][9216]
    _Float16* yi = (_Float16*)ws;   ws += 42467328;   // [9216][2304] fp16 softmax; later aliased by P
    _Float16* Wt = (_Float16*)ws;   ws += 10616832;   // [2304][2304] fp16 raw_w^T; later aliased by yth
    _Float16* xp = (_Float16*)ws;   ws += 5308416;    // [9216][288] fp16
    _Float16* wn = (_Float16*)ws;   ws += 1327104;    // [2304][288] fp16 (x10 folded)
    float* embed = (float*)ws;      ws += 2359296;    // [64][96][96]
    float* match = (float*)ws;      ws += 1179648;    // [32][96][96]
    float* pooled = (float*)ws;     ws += 589824;     // [64][48][48]
    float* refb = (float*)ws;       ws += 294912;     // [32][48][48]
    _Float16* Wdh = (_Float16*)ws;  ws += 147456;     // [128][576] fp16 (rows 64+ zero)
    // aliases (producer of the alias runs strictly after the last read of the host buffer)
    _Float16* P = yi;     // [9216][576] fp16 im2col — built after GEMM2 consumed yi
    _Float16* yth = Wt;   // [64][192][192] fp16 — written after GEMM2 consumed Wt

    build_Wdh<<<288, 256, 0, stream>>>(Wd, Wdh);

    for (int b = 0; b < 2; ++b) {
        const float* xb = x + (size_t)b * 64 * 9216;
        float* outb = out + (size_t)b * 64 * 9216;

        pool2_kernel<<<576, 256, 0, stream>>>(xb, pooled);
        conv1x1_prelu<64><<<36, 256, 0, stream>>>(xb, Wa, ba, aa, embed, 64, 9216);
        conv1x1_prelu<64><<<36, 256, 0, stream>>>(xb, W1, b1, a1, match, 32, 9216);
        conv1x1_prelu<64><<<9, 256, 0, stream>>>(pooled, W2, b2, a2, refb, 32, 2304);
        build_xp<<<1152, 256, 0, stream>>>(match, xp);
        build_wn<<<2304, 64, 0, stream>>>(refb, wn);
        build_Wt<<<20736, 256, 0, stream>>>(embed, Wt);

        // GEMM1: S[q][l] = <xp[q], wn[l]> (x10 folded into wn)
        gemm16<0><<<dim3(18, 72), 256, 0, stream>>>(xp, wn, 9216, 2304, 288, S, nullptr);
        softmax_rows<<<9216, 256, 0, stream>>>(S, yi);

        // GEMM2: Z[(oij)][q] = sum_l Wt[(oij)][l] * yi[q][l]  (plain store into S)
        gemm16<0><<<dim3(72, 18), 256, 0, stream>>>(Wt, yi, 2304, 9216, 2304, S, nullptr);

        gather_yt<<<9216, 256, 0, stream>>>(S, yth);
        build_P<<<2304, 256, 0, stream>>>(yth, P);
        // GEMM3 (down conv): out[op][q] = (sum_k Wdh[op][k] P[q][k] + bd[op]) / 6
        gemm16<2><<<dim3(72, 1), 256, 0, stream>>>(Wdh, P, 128, 9216, 576, outb, bd);
    }
}

// Round 5
// 681.341 us; speedup vs baseline: 2.6217x; 1.4656x over previous
//
#include <hip/hip_runtime.h>

typedef _Float16 half8 __attribute__((ext_vector_type(8)));
typedef float float4v __attribute__((ext_vector_type(4)));

// ---------------------------------------------------------------- small ops

__global__ void pool2_kernel(const float* __restrict__ in, float* __restrict__ out) {
    // [64][96][96] -> [64][48][48], 2x2 mean
    int i = blockIdx.x * 256 + threadIdx.x;
    if (i >= 64 * 48 * 48) return;
    int c = i / 2304, r = i % 2304, ph = r / 48, pw = r % 48;
    const float* p = in + c * 9216 + ph * 2 * 96 + pw * 2;
    out[i] = 0.25f * (p[0] + p[1] + p[96] + p[97]);
}

// fused conv1x1+prelu for embed (64 ch, Wa) and match (32 ch, W1); x read once per
// co-chunk. grid (36, 6): chunks 0-3 -> embed co 0..63, chunks 4-5 -> match co 0..31.
__global__ __launch_bounds__(256) void conv_embed_match(
    const float* __restrict__ x, const float* __restrict__ Wa, const float* __restrict__ ba,
    const float* __restrict__ aa, const float* __restrict__ W1, const float* __restrict__ b1,
    const float* __restrict__ a1, float* __restrict__ embed, float* __restrict__ match) {
    int p = blockIdx.x * 256 + threadIdx.x;  // 9216 pixels
    int chunk = blockIdx.y;
    float xin[64];
#pragma unroll
    for (int ci = 0; ci < 64; ++ci) xin[ci] = x[ci * 9216 + p];
    bool isE = chunk < 4;
    int co0 = (isE ? chunk : chunk - 4) * 16;
    const float* W = isE ? Wa : W1;
    const float* bb = isE ? ba : b1;
    float alpha = (isE ? aa : a1)[0];
    float* dst = isE ? embed : match;
#pragma unroll
    for (int c = 0; c < 16; ++c) {
        int co = co0 + c;
        float s = bb[co];
#pragma unroll
        for (int ci = 0; ci < 64; ++ci) s += W[co * 64 + ci] * xin[ci];
        dst[co * 9216 + p] = s >= 0.f ? s : alpha * s;
    }
}

// co-tiled conv1x1+prelu (CIN=64), 16 outputs per block-row. grid (npix/256, Cout/16)
__global__ __launch_bounds__(256) void conv1x1_tile(const float* __restrict__ in,
                                                    const float* __restrict__ W,
                                                    const float* __restrict__ bias,
                                                    const float* __restrict__ a,
                                                    float* __restrict__ out, int npix) {
    int p = blockIdx.x * 256 + threadIdx.x;
    if (p >= npix) return;
    int co0 = blockIdx.y * 16;
    float xin[64];
#pragma unroll
    for (int ci = 0; ci < 64; ++ci) xin[ci] = in[ci * npix + p];
    float alpha = a[0];
#pragma unroll
    for (int c = 0; c < 16; ++c) {
        int co = co0 + c;
        float s = bias[co];
#pragma unroll
        for (int ci = 0; ci < 64; ++ci) s += W[co * 64 + ci] * xin[ci];
        out[co * npix + p] = s >= 0.f ? s : alpha * s;
    }
}

// xp[q][k=c*9+kh*3+kw] = match[c][qh+kh-1][qw+kw-1] (zero pad), fp16.
// wave per q, lane-contiguous k -> coalesced short stores. grid 2304 x 256.
__global__ __launch_bounds__(256) void build_xp(const float* __restrict__ match,
                                                _Float16* __restrict__ xp) {
    int q = blockIdx.x * 4 + (threadIdx.x >> 6);
    int lane = threadIdx.x & 63;
    int qh = q / 96, qw = q % 96;
#pragma unroll
    for (int t = 0; t < 5; ++t) {
        int k = lane + t * 64;
        if (k < 288) {
            int c = k / 9, r = k % 9;
            int y = qh + r / 3 - 1, x = qw + r % 3 - 1;
            float v = (y >= 0 && y < 96 && x >= 0 && x < 96) ? match[c * 9216 + y * 96 + x] : 0.f;
            xp[(size_t)q * 288 + k] = (_Float16)v;
        }
    }
}

// wn[l][c*9+kh*3+kw] = 10 * patch / max(||patch||, 1e-4), fp16.  1 wave per l.
__global__ void build_wn(const float* __restrict__ ref, _Float16* __restrict__ wn) {
    int l = blockIdx.x;  // 2304
    int oh = l / 48, ow = l % 48;
    int lane = threadIdx.x;  // 64
    float vals[5];
    float ss = 0.f;
#pragma unroll
    for (int t = 0; t < 5; ++t) {
        int i = lane + t * 64;
        float v = 0.f;
        if (i < 288) {
            int c = i / 9, r = i % 9, kh = r / 3, kw = r % 3;
            int y = oh + kh - 1, x = ow + kw - 1;
            v = (y >= 0 && y < 48 && x >= 0 && x < 48) ? ref[c * 2304 + y * 48 + x] : 0.f;
        }
        vals[t] = v;
        ss += v * v;
    }
#pragma unroll
    for (int d = 32; d; d >>= 1) ss += __shfl_xor(ss, d);
    float norm = sqrtf(ss);
    norm = norm < 1e-4f ? 1e-4f : norm;
    float inv = 10.f / norm;  // fold SOFTMAX_SCALE here
#pragma unroll
    for (int t = 0; t < 5; ++t) {
        int i = lane + t * 64;
        if (i < 288) wn[(size_t)l * 288 + i] = (_Float16)(vals[t] * inv);
    }
}

// Wt[row=(o*36+i*6+j)][l=(lh*48+lw)] = embed[o][2lh+i-2][2lw+j-2] (zero pad), fp16
__global__ void build_Wt(const float* __restrict__ embed, _Float16* __restrict__ Wt) {
    int idx = blockIdx.x * 256 + threadIdx.x;
    if (idx >= 2304 * 2304) return;
    int row = idx / 2304, l = idx % 2304;
    int o = row / 36, rem = row % 36, i = rem / 6, j = rem % 6;
    int lh = l / 48, lw = l % 48;
    int y = 2 * lh + i - 2, x = 2 * lw + j - 2;
    float v = (y >= 0 && y < 96 && x >= 0 && x < 96) ? embed[o * 9216 + y * 96 + x] : 0.f;
    Wt[idx] = (_Float16)v;
}

// row softmax over l=2304 per q, writes fp16 normalized weights
__global__ __launch_bounds__(256) void softmax_rows(const float* __restrict__ S,
                                                    _Float16* __restrict__ yi) {
    int q = blockIdx.x;
    const float* row = S + (size_t)q * 2304;
    int tid = threadIdx.x;
    float v[9];
    float m = -1e30f;
#pragma unroll
    for (int t = 0; t < 9; ++t) {
        v[t] = row[tid + t * 256];
        m = fmaxf(m, v[t]);
    }
    __shared__ float red[8];
#pragma unroll
    for (int d = 32; d; d >>= 1) m = fmaxf(m, __shfl_xor(m, d));
    if ((tid & 63) == 0) red[tid >> 6] = m;
    __syncthreads();
    m = fmaxf(fmaxf(red[0], red[1]), fmaxf(red[2], red[3]));
    float s = 0.f;
#pragma unroll
    for (int t = 0; t < 9; ++t) {
        v[t] = expf(v[t] - m);
        s += v[t];
    }
#pragma unroll
    for (int d = 32; d; d >>= 1) s += __shfl_xor(s, d);
    __syncthreads();
    if ((tid & 63) == 0) red[(tid >> 6) + 4] = s;
    __syncthreads();
    s = red[4] + red[5] + red[6] + red[7];
    float inv = 1.f / s;
    _Float16* orow = yi + (size_t)q * 2304;
#pragma unroll
    for (int t = 0; t < 9; ++t) orow[tid + t * 256] = (_Float16)(v[t] * inv);
}

// ---------------------------------------------------------------- MFMA GEMM
// C[M][N] = sum_k A[M][K] * B[N][K]  (K-contiguous fp16), fp32 accum.
// MODE 0: fp32 store.  MODE 1: fp16 store (Z).  MODE 2: rows<64, (acc+bias)/6.
// Staging: global_load_lds width-16. Tile = 128 rows x 32 halves = 8 x 1KB chunks
// per matrix; each wave issues 2 A-chunks + 2 B-chunks (c = wave*2 + r, r<2).
// XOR swizzle slot = cc ^ ((row>>1)&3) keeps ds_read_b128 at 2-way/bank (free).
template <int MODE>
__global__ __launch_bounds__(256) void gemm16(const _Float16* __restrict__ A,
                                              const _Float16* __restrict__ B, int M, int N, int K,
                                              void* __restrict__ outv,
                                              const float* __restrict__ bias) {
    __shared__ _Float16 As[128 * 32];
    __shared__ _Float16 Bs[128 * 32];
    int tid = threadIdx.x;
    int wave = tid >> 6, lane = tid & 63;
    int wm = wave >> 1, wn_ = wave & 1;  // 2x2 wave grid, 64x64 per wave
    int quad = lane >> 4, mrow = lane & 15;
    int m0 = blockIdx.y * 128, n0 = blockIdx.x * 128;
    int lrow = lane >> 2, lslot = lane & 3;
    float4v acc[4][4] = {};

    for (int k0 = 0; k0 < K; k0 += 32) {
        // chunk c = rows [c*16, c*16+16); lane writes LDS at chunk_base + lane*16B
        // (hardware layout), so source element = (row = c*16 + lane/4,
        //  cc = (lane&3) ^ ((row>>1)&3)) — the inverse of the read swizzle.
#pragma unroll
        for (int r = 0; r < 2; ++r) {
            int c = wave * 2 + r;  // 0..7 — exactly 8 chunks per matrix
            int row = c * 16 + lrow;
            int cc = lslot ^ ((row >> 1) & 3);
            const _Float16* ga = A + (size_t)(m0 + row) * K + k0 + cc * 8;
            const _Float16* gb = B + (size_t)(n0 + row) * K + k0 + cc * 8;
            __builtin_amdgcn_global_load_lds(
                (const __attribute__((address_space(1))) unsigned int*)ga,
                (__attribute__((address_space(3))) unsigned int*)&As[c * 512], 16, 0, 0);
            __builtin_amdgcn_global_load_lds(
                (const __attribute__((address_space(1))) unsigned int*)gb,
                (__attribute__((address_space(3))) unsigned int*)&Bs[c * 512], 16, 0, 0);
        }
        __syncthreads();
        half8 af[4], bf[4];
#pragma unroll
        for (int t = 0; t < 4; ++t) {
            int arow = wm * 64 + t * 16 + mrow;
            af[t] = *(const half8*)&As[arow * 32 + (quad ^ ((arow >> 1) & 3)) * 8];
            int brow = wn_ * 64 + t * 16 + mrow;
            bf[t] = *(const half8*)&Bs[brow * 32 + (quad ^ ((brow >> 1) & 3)) * 8];
        }
#pragma unroll
        for (int i = 0; i < 4; ++i)
#pragma unroll
            for (int j = 0; j < 4; ++j)
                acc[i][j] = __builtin_amdgcn_mfma_f32_16x16x32_f16(af[i], bf[j], acc[i][j], 0, 0, 0);
        __syncthreads();
    }

    // epilogue: D row m = quad*4+r (M dim), col n = lane&15 (N dim)
#pragma unroll
    for (int i = 0; i < 4; ++i)
#pragma unroll
        for (int j = 0; j < 4; ++j)
#pragma unroll
            for (int r = 0; r < 4; ++r) {
                int row = m0 + wm * 64 + i * 16 + quad * 4 + r;
                int col = n0 + wn_ * 64 + j * 16 + mrow;
                float v = acc[i][j][r];
                if (MODE == 0) {
                    ((float*)outv)[(size_t)row * N + col] = v;
                } else if (MODE == 1) {
                    ((_Float16*)outv)[(size_t)row * N + col] = (_Float16)v;
                } else {
                    if (row < 64)
                        ((float*)outv)[(size_t)row * N + col] = (v + bias[row]) * (1.f / 6.f);
                }
            }
}

// gather (inverse of tconv scatter): yth[o][Y][X] = sum_{i==Y%2, j==X%2 (mod 2)}
//   Z[(o*36+i*6+j)][h*96+w]  with h=(Y+2-i)/2, w=(X+2-j)/2 in range. fp16 in/out.
__global__ void gather_yt(const _Float16* __restrict__ Z, _Float16* __restrict__ yth) {
    int idx = blockIdx.x * 256 + threadIdx.x;
    if (idx >= 64 * 192 * 192) return;
    int o = idx / 36864, r = idx % 36864, Y = r / 192, X = r % 192;
    float s = 0.f;
    for (int i = Y & 1; i < 6; i += 2) {
        int h2 = Y + 2 - i;
        if (h2 < 0) continue;
        int h = h2 >> 1;
        if (h >= 96) continue;
        for (int j = X & 1; j < 6; j += 2) {
            int w2 = X + 2 - j;
            if (w2 < 0) continue;
            int w = w2 >> 1;
            if (w >= 96) continue;
            s += (float)Z[(size_t)(o * 36 + i * 6 + j) * 9216 + h * 96 + w];
        }
    }
    yth[idx] = (_Float16)s;
}

// im2col for the down conv (3x3, stride 2, pad 1), wave per q, lane-contiguous k:
// P[q=(y*96+x)][k=o*9+dy*3+dx] = yth[o][2y-1+dy][2x-1+dx] (zero pad), fp16.
// 576 = 9*64 -> exactly 9 full chunks, no bounds check on k. grid 2304 x 256.
__global__ __launch_bounds__(256) void build_P(const _Float16* __restrict__ yth,
                                               _Float16* __restrict__ P) {
    int q = blockIdx.x * 4 + (threadIdx.x >> 6);
    int lane = threadIdx.x & 63;
    int y = q / 96, x = q % 96;
#pragma unroll
    for (int t = 0; t < 9; ++t) {
        int k = lane + t * 64;
        int o = k / 9, r = k % 9;
        int Y = 2 * y - 1 + r / 3, X = 2 * x - 1 + r % 3;
        _Float16 v = (_Float16)0.f;
        if (Y >= 0 && Y < 192 && X >= 0 && X < 192) v = yth[o * 36864 + Y * 192 + X];
        P[(size_t)q * 576 + k] = v;
    }
}

// Wdh[op][k] fp16, rows 64..127 zero-padded (so the 128-row GEMM tile is safe)
__global__ void build_Wdh(const float* __restrict__ Wd, _Float16* __restrict__ Wdh) {
    int idx = blockIdx.x * 256 + threadIdx.x;
    if (idx >= 128 * 576) return;
    int op = idx / 576;
    Wdh[idx] = (_Float16)(op < 64 ? Wd[idx] : 0.f);  // Wd[(op*64+o)*9+k] == Wd[op*576+...]
}

// ---------------------------------------------------------------- launch

extern "C" void kernel_launch(void* const* d_in, const int* in_sizes, int n_in,
                              void* d_out, int out_size, void* d_ws, size_t ws_size,
                              hipStream_t stream) {
    const float* x = (const float*)d_in[0];
    const float* W1 = (const float*)d_in[1];
    const float* b1 = (const float*)d_in[2];
    const float* a1 = (const float*)d_in[3];
    const float* W2 = (const float*)d_in[4];
    const float* b2 = (const float*)d_in[5];
    const float* a2 = (const float*)d_in[6];
    const float* Wa = (const float*)d_in[7];
    const float* ba = (const float*)d_in[8];
    const float* aa = (const float*)d_in[9];
    const float* Wd = (const float*)d_in[10];
    const float* bd = (const float*)d_in[11];
    float* out = (float*)d_out;

    char* ws = (char*)d_ws;
    float* S = (float*)ws;          ws += 84934656;   // [9216][2304] fp32 logits; Z fp16 aliases front half
    _Float16* yi = (_Float16*)ws;   ws += 42467328;   // [9216][2304] fp16 softmax; P aliases after GEMM2
    _Float16* Wt = (_Float16*)ws;   ws += 10616832;   // [2304][2304] fp16 raw_w^T; yth aliases after GEMM2
    _Float16* xp = (_Float16*)ws;   ws += 5308416;    // [9216][288] fp16
    _Float16* wn = (_Float16*)ws;   ws += 1327104;    // [2304][288] fp16 (x10 folded)
    float* embed = (float*)ws;      ws += 2359296;    // [64][96][96]
    float* match = (float*)ws;      ws += 1179648;    // [32][96][96]
    float* pooled = (float*)ws;     ws += 589824;     // [64][48][48]
    float* refb = (float*)ws;       ws += 294912;     // [32][48][48]
    _Float16* Wdh = (_Float16*)ws;  ws += 147456;     // [128][576] fp16 (rows 64+ zero)
    // aliases (producer of the alias runs strictly after the last read of the host buffer)
    _Float16* Z = (_Float16*)S;  // [2304][9216] fp16 — written after softmax consumed S
    _Float16* P = yi;            // [9216][576] fp16 im2col — built after GEMM2 consumed yi
    _Float16* yth = Wt;          // [64][192][192] fp16 — written after GEMM2 consumed Wt

    build_Wdh<<<288, 256, 0, stream>>>(Wd, Wdh);

    for (int b = 0; b < 2; ++b) {
        const float* xb = x + (size_t)b * 64 * 9216;
        float* outb = out + (size_t)b * 64 * 9216;

        pool2_kernel<<<576, 256, 0, stream>>>(xb, pooled);
        conv_embed_match<<<dim3(36, 6), 256, 0, stream>>>(xb, Wa, ba, aa, W1, b1, a1, embed, match);
        conv1x1_tile<<<dim3(9, 2), 256, 0, stream>>>(pooled, W2, b2, a2, refb, 2304);
        build_xp<<<2304, 256, 0, stream>>>(match, xp);
        build_wn<<<2304, 64, 0, stream>>>(refb, wn);
        build_Wt<<<20736, 256, 0, stream>>>(embed, Wt);

        // GEMM1: S[q][l] = <xp[q], wn[l]> (x10 folded into wn)
        gemm16<0><<<dim3(18, 72), 256, 0, stream>>>(xp, wn, 9216, 2304, 288, S, nullptr);
        softmax_rows<<<9216, 256, 0, stream>>>(S, yi);

        // GEMM2: Z[(oij)][q] = sum_l Wt[(oij)][l] * yi[q][l]  (fp16 store into S-alias)
        gemm16<1><<<dim3(72, 18), 256, 0, stream>>>(Wt, yi, 2304, 9216, 2304, Z, nullptr);

        gather_yt<<<9216, 256, 0, stream>>>(Z, yth);
        build_P<<<2304, 256, 0, stream>>>(yth, P);
        // GEMM3 (down conv): out[op][q] = (sum_k Wdh[op][k] P[q][k] + bd[op]) / 6
        gemm16<2><<<dim3(72, 1), 256, 0, stream>>>(Wdh, P, 128, 9216, 576, outb, bd);
    }
}